// Round 1
// baseline (525.331 us; speedup 1.0000x reference)
//
#include <hip/hip_runtime.h>
#include <stdint.h>

// ExpertLoRA: E=8,H=2048,D=2048,F=1024,T=2048,K=4,R=8, SCALING=2, LIMIT=7, alpha=1.702
// Pipeline:
//  k_route   : w[E][T], per-expert token lists (+int64/int32 detect on device)
//  k_prefix  : prefix-sum of counts -> packed row offsets
//  k_wprep   : W1eff^T = (W1 + 2*A1@B1)^T -> bf16 [E][D][H]; same for W2eff^T [E][H][F]
//              (LoRA folded exactly: x@W + 2*(x@A)@B == x@(W+2AB))
//  k_xconv   : X fp32 -> bf16 [T][H]
//  k_gemm1   : per-expert [Me,2048] = Xg @ W1eff^T, +bias, clamped-GLU -> gated bf16 [pairs][F]
//  k_gemm2   : per-expert [Me,2048] = gated @ W2eff^T, +bias, atomicAdd(w[e,t]*val) into out
// ws layout (needs ~121 MB):
//  cnt@0(32B), offs@64, w@4K(64KB), list@128K(64KB), Xb@1M(8MB),
//  gated@9M(16MB), W2T@25M(32MB), W1T@57M(64MB)

typedef short bf16x8 __attribute__((ext_vector_type(8)));
typedef float f32x4 __attribute__((ext_vector_type(4)));

__device__ __forceinline__ short bf16r(float f) {
  uint32_t u = __float_as_uint(f);
  u += 0x7fffu + ((u >> 16) & 1u);
  return (short)(u >> 16);
}

__device__ __forceinline__ void load_lds16(const void* g, void* l) {
  __builtin_amdgcn_global_load_lds((const __attribute__((address_space(1))) void*)g,
                                   (__attribute__((address_space(3))) void*)l,
                                   16, 0, 0);
}

__global__ void k_route(const int* __restrict__ idx_raw, const float* __restrict__ rw,
                        float* __restrict__ w, int* __restrict__ cnt, int* __restrict__ list) {
  __shared__ int s_nz;
  const int tid = threadIdx.x;
  if (tid == 0) s_nz = 0;
  __syncthreads();
  // int64 vs int32 detection: if indices are int64 (values 0..7), every odd 32-bit
  // word of the first 8192 words is 0. For int32, odd words are random 0..7.
  int found = 0;
  for (int i = tid; i < 4096; i += 256) found |= idx_raw[2 * i + 1];
  if (found) atomicOr(&s_nz, 1);
  __syncthreads();
  const bool is64 = (s_nz == 0);

  const int t = blockIdx.x * 256 + tid;  // token; grid = 8 blocks x 256
  int ek[4]; float rk[4];
#pragma unroll
  for (int k = 0; k < 4; k++) {
    ek[k] = is64 ? idx_raw[2 * (t * 4 + k)] : idx_raw[t * 4 + k];
    rk[k] = rw[t * 4 + k];
  }
#pragma unroll
  for (int e = 0; e < 8; e++) {
    float s = 0.f;
#pragma unroll
    for (int k = 0; k < 4; k++) s += (ek[k] == e) ? rk[k] : 0.f;
    w[e * 2048 + t] = s;
    if (s != 0.f) {
      int slot = atomicAdd(&cnt[e], 1);
      list[e * 2048 + slot] = t;
    }
  }
}

__global__ void k_prefix(const int* __restrict__ cnt, int* __restrict__ offs) {
  if (threadIdx.x == 0 && blockIdx.x == 0) {
    int s = 0;
    for (int e = 0; e < 8; e++) { offs[e] = s; s += cnt[e]; }
    offs[8] = s;
  }
}

// O[e][n][k] = bf16( W[e][k][n] + 2 * sum_r A[e][k][r]*Bm[e][r][n] )
__global__ void k_wprep(const float* __restrict__ W, const float* __restrict__ A,
                        const float* __restrict__ Bm, short* __restrict__ O,
                        int Kd, int Nd) {
  const int e = blockIdx.z;
  const float* We = W + (size_t)e * Kd * Nd;
  const float* Ae = A + (size_t)e * Kd * 8;
  const float* Be = Bm + (size_t)e * 8 * Nd;
  short* Oe = O + (size_t)e * Kd * Nd;
  __shared__ float tile[32][33];
  __shared__ float As[32][9];
  __shared__ float Bs[8][32];
  const int n0 = blockIdx.x * 32, k0 = blockIdx.y * 32;
  const int tx = threadIdx.x & 31, ty = threadIdx.x >> 5;  // 32 x 8
#pragma unroll
  for (int i = 0; i < 4; i++)
    tile[ty + 8 * i][tx] = We[(size_t)(k0 + ty + 8 * i) * Nd + n0 + tx];
  {
    int kk = threadIdx.x >> 3, r = threadIdx.x & 7;
    As[kk][r] = Ae[(size_t)(k0 + kk) * 8 + r];
  }
  {
    int rr = threadIdx.x >> 5, nn = threadIdx.x & 31;
    Bs[rr][nn] = Be[(size_t)rr * Nd + n0 + nn];
  }
  __syncthreads();
#pragma unroll
  for (int i = 0; i < 4; i++) {
    int n = ty + 8 * i;
    float v = tile[tx][n];
    float l = 0.f;
#pragma unroll
    for (int r = 0; r < 8; r++) l += As[tx][r] * Bs[r][n];
    Oe[(size_t)(n0 + n) * Kd + k0 + tx] = bf16r(v + 2.0f * l);
  }
}

__global__ void k_xconv(const float* __restrict__ x, short* __restrict__ xb) {
  const int i = (blockIdx.x * 256 + threadIdx.x) * 4;
  float4 v = *(const float4*)(x + i);
  short4 s;
  s.x = bf16r(v.x); s.y = bf16r(v.y); s.z = bf16r(v.z); s.w = bf16r(v.w);
  *(short4*)(xb + i) = s;
}

// GEMM1: per expert e, C[slot, d] = Xg @ W1T^T  (M=cnt[e], N=2048, K=2048)
// epilogue: +bias, clamped GLU -> gated bf16 [off_e+slot][f]
__global__ __launch_bounds__(256) void k_gemm1(
    const short* __restrict__ Xb, const short* __restrict__ W1T,
    const float* __restrict__ bias1, const int* __restrict__ cnt,
    const int* __restrict__ offs, const int* __restrict__ list,
    short* __restrict__ gated) {
  const int e = blockIdx.z;
  const int M = cnt[e];
  const int m0 = blockIdx.y * 128;
  if (m0 >= M) return;
  const int n0 = blockIdx.x * 128;
  const short* Be = W1T + (size_t)e * 2048 * 2048;
  const int* le = list + e * 2048;
  const int off_e = offs[e];

  __shared__ __align__(16) short sA[128 * 32];
  __shared__ __align__(16) short sB[128 * 32];

  const int tid = threadIdx.x;
  const int r0 = tid >> 2;            // 0..63
  const int kq = (tid & 3) << 3;      // 0,8,16,24
  const int t0 = le[min(m0 + r0, M - 1)];
  const int t1 = le[min(m0 + r0 + 64, M - 1)];
  const short* ga0 = Xb + (size_t)t0 * 2048 + kq;
  const short* ga1 = Xb + (size_t)t1 * 2048 + kq;
  const short* gb0 = Be + (size_t)(n0 + r0) * 2048 + kq;
  const short* gb1 = Be + (size_t)(n0 + r0 + 64) * 2048 + kq;
  short* lA0 = sA + tid * 8;
  short* lA1 = sA + 2048 + tid * 8;
  short* lB0 = sB + tid * 8;
  short* lB1 = sB + 2048 + tid * 8;

  const int lane = tid & 63;
  const int wave = tid >> 6;
  const int wm = (wave & 1) * 64;
  const int wn = (wave >> 1) * 64;
  const int lm = lane & 15;
  const int quad = lane >> 4;

  f32x4 acc[4][4];
#pragma unroll
  for (int i = 0; i < 4; i++)
#pragma unroll
    for (int j = 0; j < 4; j++) acc[i][j] = (f32x4){0.f, 0.f, 0.f, 0.f};

  for (int kt = 0; kt < 64; kt++) {
    load_lds16(ga0, lA0);
    load_lds16(ga1, lA1);
    load_lds16(gb0, lB0);
    load_lds16(gb1, lB1);
    ga0 += 32; ga1 += 32; gb0 += 32; gb1 += 32;
    __syncthreads();
    bf16x8 a[4], b[4];
#pragma unroll
    for (int mi = 0; mi < 4; mi++)
      a[mi] = *(const bf16x8*)(sA + (wm + mi * 16 + lm) * 32 + quad * 8);
#pragma unroll
    for (int ni = 0; ni < 4; ni++)
      b[ni] = *(const bf16x8*)(sB + (wn + ni * 16 + lm) * 32 + quad * 8);
#pragma unroll
    for (int mi = 0; mi < 4; mi++)
#pragma unroll
      for (int ni = 0; ni < 4; ni++)
        acc[mi][ni] = __builtin_amdgcn_mfma_f32_16x16x32_bf16(a[mi], b[ni], acc[mi][ni], 0, 0, 0);
    __syncthreads();
  }

  const float* be = bias1 + e * 2048;
#pragma unroll
  for (int mi = 0; mi < 4; mi++) {
    const int rbase = m0 + wm + mi * 16 + quad * 4;
#pragma unroll
    for (int ni = 0; ni < 4; ni++) {
      const int col = n0 + wn + ni * 16 + lm;  // d index; parity == lane parity
      const float bias = be[col];
#pragma unroll
      for (int r = 0; r < 4; r++) {
        const int slot = rbase + r;
        float val = acc[mi][ni][r] + bias;
        float other = __shfl_xor(val, 1);  // partner holds the 'up' column
        if (((lane & 1) == 0) && (slot < M)) {
          float g = fminf(val, 7.f);
          float u = fminf(fmaxf(other, -7.f), 7.f);
          float glu = g / (1.f + __expf(-1.702f * g));
          float gv = (u + 1.f) * glu;
          gated[(size_t)(off_e + slot) * 1024 + (col >> 1)] = bf16r(gv);
        }
      }
    }
  }
}

// GEMM2: per expert e, C[slot, h] = gated @ W2T^T (M=cnt[e], N=2048, K=1024)
// epilogue: out[t,h] += w[e,t] * (C + bias2)
__global__ __launch_bounds__(256) void k_gemm2(
    const short* __restrict__ gated, const short* __restrict__ W2T,
    const float* __restrict__ bias2, const float* __restrict__ wbuf,
    const int* __restrict__ cnt, const int* __restrict__ offs,
    const int* __restrict__ list, float* __restrict__ out) {
  const int e = blockIdx.z;
  const int M = cnt[e];
  const int m0 = blockIdx.y * 128;
  if (m0 >= M) return;
  const int n0 = blockIdx.x * 128;
  const int off_e = offs[e];
  const short* Ae = gated + (size_t)off_e * 1024;
  const short* Be = W2T + (size_t)e * 2048 * 1024;
  const int* le = list + e * 2048;

  __shared__ __align__(16) short sA[128 * 32];
  __shared__ __align__(16) short sB[128 * 32];

  const int tid = threadIdx.x;
  const int r0 = tid >> 2;
  const int kq = (tid & 3) << 3;
  const short* ga0 = Ae + (size_t)min(m0 + r0, M - 1) * 1024 + kq;
  const short* ga1 = Ae + (size_t)min(m0 + r0 + 64, M - 1) * 1024 + kq;
  const short* gb0 = Be + (size_t)(n0 + r0) * 1024 + kq;
  const short* gb1 = Be + (size_t)(n0 + r0 + 64) * 1024 + kq;
  short* lA0 = sA + tid * 8;
  short* lA1 = sA + 2048 + tid * 8;
  short* lB0 = sB + tid * 8;
  short* lB1 = sB + 2048 + tid * 8;

  const int lane = tid & 63;
  const int wave = tid >> 6;
  const int wm = (wave & 1) * 64;
  const int wn = (wave >> 1) * 64;
  const int lm = lane & 15;
  const int quad = lane >> 4;

  f32x4 acc[4][4];
#pragma unroll
  for (int i = 0; i < 4; i++)
#pragma unroll
    for (int j = 0; j < 4; j++) acc[i][j] = (f32x4){0.f, 0.f, 0.f, 0.f};

  for (int kt = 0; kt < 32; kt++) {
    load_lds16(ga0, lA0);
    load_lds16(ga1, lA1);
    load_lds16(gb0, lB0);
    load_lds16(gb1, lB1);
    ga0 += 32; ga1 += 32; gb0 += 32; gb1 += 32;
    __syncthreads();
    bf16x8 a[4], b[4];
#pragma unroll
    for (int mi = 0; mi < 4; mi++)
      a[mi] = *(const bf16x8*)(sA + (wm + mi * 16 + lm) * 32 + quad * 8);
#pragma unroll
    for (int ni = 0; ni < 4; ni++)
      b[ni] = *(const bf16x8*)(sB + (wn + ni * 16 + lm) * 32 + quad * 8);
#pragma unroll
    for (int mi = 0; mi < 4; mi++)
#pragma unroll
      for (int ni = 0; ni < 4; ni++)
        acc[mi][ni] = __builtin_amdgcn_mfma_f32_16x16x32_bf16(a[mi], b[ni], acc[mi][ni], 0, 0, 0);
    __syncthreads();
  }

  const float* be = bias2 + e * 2048;
#pragma unroll
  for (int mi = 0; mi < 4; mi++) {
#pragma unroll
    for (int r = 0; r < 4; r++) {
      const int slot = m0 + wm + mi * 16 + quad * 4 + r;
      if (slot >= M) continue;
      const int token = le[slot];
      const float wt = wbuf[e * 2048 + token];
      float* orow = out + (size_t)token * 2048;
#pragma unroll
      for (int ni = 0; ni < 4; ni++) {
        const int h = n0 + wn + ni * 16 + lm;
        atomicAdd(orow + h, wt * (acc[mi][ni][r] + be[h]));
      }
    }
  }
}

extern "C" void kernel_launch(void* const* d_in, const int* in_sizes, int n_in,
                              void* d_out, int out_size, void* d_ws, size_t ws_size,
                              hipStream_t stream) {
  const float* x   = (const float*)d_in[0];
  const float* rw  = (const float*)d_in[1];
  const float* w1  = (const float*)d_in[2];
  const float* b1  = (const float*)d_in[3];
  const float* w2  = (const float*)d_in[4];
  const float* b2  = (const float*)d_in[5];
  const float* a1  = (const float*)d_in[6];
  const float* lb1 = (const float*)d_in[7];
  const float* a2  = (const float*)d_in[8];
  const float* lb2 = (const float*)d_in[9];
  const int* idx   = (const int*)d_in[10];
  float* out = (float*)d_out;

  char* ws = (char*)d_ws;
  int* cnt    = (int*)(ws);
  int* offs   = (int*)(ws + 64);
  float* wbuf = (float*)(ws + 4096);
  int* list   = (int*)(ws + 131072);
  short* Xb   = (short*)(ws + (1ull << 20));
  short* gated= (short*)(ws + 9437184ull);
  short* W2T  = (short*)(ws + 26214400ull);
  short* W1T  = (short*)(ws + 59768832ull);   // needs ws_size >= ~121 MB

  hipMemsetAsync(out, 0, (size_t)2048 * 2048 * 4, stream);
  hipMemsetAsync(cnt, 0, 64, stream);

  k_route<<<dim3(8), dim3(256), 0, stream>>>(idx, rw, wbuf, cnt, list);
  k_prefix<<<dim3(1), dim3(64), 0, stream>>>(cnt, offs);
  k_wprep<<<dim3(64, 64, 8), dim3(256), 0, stream>>>(w1, a1, lb1, W1T, 2048, 2048);
  k_wprep<<<dim3(64, 32, 8), dim3(256), 0, stream>>>(w2, a2, lb2, W2T, 1024, 2048);
  k_xconv<<<dim3(4096), dim3(256), 0, stream>>>(x, Xb);
  k_gemm1<<<dim3(16, 16, 8), dim3(256), 0, stream>>>(Xb, W1T, b1, cnt, offs, list, gated);
  k_gemm2<<<dim3(16, 16, 8), dim3(256), 0, stream>>>(gated, W2T, b2, wbuf, cnt, offs, list, out);
}

// Round 2
// 465.357 us; speedup vs baseline: 1.1289x; 1.1289x over previous
//
#include <hip/hip_runtime.h>
#include <stdint.h>

// ExpertLoRA: E=8,H=2048,D=2048,F=1024,T=2048,K=4,R=8, SCALING=2, LIMIT=7, alpha=1.702
// Pipeline:
//  k_route   : w[E][T], per-expert token lists, per-token (e,slot) hit list
//  k_prefix  : prefix-sum of counts -> packed row offsets
//  k_wprep   : W1eff^T = (W1 + 2*A1@B1)^T -> bf16 [E][D][H]; same for W2eff^T [E][H][F]
//  k_xconv   : X fp32 -> bf16 [T][H]
//  k_gemm1   : per-expert [Me,2048] = Xg @ W1eff^T, +bias, clamped-GLU -> gated bf16
//  k_gemm2   : per-expert [Me,2048] = gated @ W2eff^T -> pairbuf bf16 (raw, no bias)
//  k_combine : out[t,h] = sum_j wt_j * (pairbuf[pair_j][h] + b2[e_j][h])  (no atomics)
// ws layout (~121 MB):
//  cnt@0, offs@64, tok_nh@128(8K), wbuf@16K(64K), list@80K(64K), tok_pair@144K(32K),
//  Xb@1M(8MB), gated@9M(16MB), W2T@25M(32MB), W1T@57M(64MB), pairbuf@57M+2.7M? no:
//  pairbuf ALIASES W1T region (gemm1 finishes before gemm2 writes pairbuf).

typedef short bf16x8 __attribute__((ext_vector_type(8)));
typedef float f32x4 __attribute__((ext_vector_type(4)));

__device__ __forceinline__ short bf16r(float f) {
  uint32_t u = __float_as_uint(f);
  u += 0x7fffu + ((u >> 16) & 1u);
  return (short)(u >> 16);
}

__device__ __forceinline__ float bf16f(short s) {
  uint32_t u = ((uint32_t)(uint16_t)s) << 16;
  return __uint_as_float(u);
}

__device__ __forceinline__ void load_lds16(const void* g, void* l) {
  __builtin_amdgcn_global_load_lds((const __attribute__((address_space(1))) void*)g,
                                   (__attribute__((address_space(3))) void*)l,
                                   16, 0, 0);
}

__global__ void k_route(const int* __restrict__ idx_raw, const float* __restrict__ rw,
                        float* __restrict__ w, int* __restrict__ cnt, int* __restrict__ list,
                        int* __restrict__ tok_nh, int* __restrict__ tok_pair) {
  __shared__ int s_nz;
  const int tid = threadIdx.x;
  if (tid == 0) s_nz = 0;
  __syncthreads();
  // int64 vs int32 detection: int64 values 0..7 -> every odd 32-bit word zero.
  int found = 0;
  for (int i = tid; i < 4096; i += 256) found |= idx_raw[2 * i + 1];
  if (found) atomicOr(&s_nz, 1);
  __syncthreads();
  const bool is64 = (s_nz == 0);

  const int t = blockIdx.x * 256 + tid;  // grid = 8 x 256
  int ek[4]; float rk[4];
#pragma unroll
  for (int k = 0; k < 4; k++) {
    ek[k] = is64 ? idx_raw[2 * (t * 4 + k)] : idx_raw[t * 4 + k];
    rk[k] = rw[t * 4 + k];
  }
  int j = 0;
#pragma unroll
  for (int e = 0; e < 8; e++) {
    float s = 0.f;
#pragma unroll
    for (int k = 0; k < 4; k++) s += (ek[k] == e) ? rk[k] : 0.f;
    w[e * 2048 + t] = s;
    if (s != 0.f) {
      int slot = atomicAdd(&cnt[e], 1);
      list[e * 2048 + slot] = t;
      tok_pair[t * 4 + j] = (e << 16) | slot;
      j++;
    }
  }
  tok_nh[t] = j;
}

__global__ void k_prefix(const int* __restrict__ cnt, int* __restrict__ offs) {
  if (threadIdx.x == 0 && blockIdx.x == 0) {
    int s = 0;
    for (int e = 0; e < 8; e++) { offs[e] = s; s += cnt[e]; }
    offs[8] = s;
  }
}

// O[e][n][k] = bf16( W[e][k][n] + 2 * sum_r A[e][k][r]*Bm[e][r][n] )
__global__ void k_wprep(const float* __restrict__ W, const float* __restrict__ A,
                        const float* __restrict__ Bm, short* __restrict__ O,
                        int Kd, int Nd) {
  const int e = blockIdx.z;
  const float* We = W + (size_t)e * Kd * Nd;
  const float* Ae = A + (size_t)e * Kd * 8;
  const float* Be = Bm + (size_t)e * 8 * Nd;
  short* Oe = O + (size_t)e * Kd * Nd;
  __shared__ float tile[32][33];
  __shared__ float As[32][9];
  __shared__ float Bs[8][32];
  const int n0 = blockIdx.x * 32, k0 = blockIdx.y * 32;
  const int tx = threadIdx.x & 31, ty = threadIdx.x >> 5;  // 32 x 8
#pragma unroll
  for (int i = 0; i < 4; i++)
    tile[ty + 8 * i][tx] = We[(size_t)(k0 + ty + 8 * i) * Nd + n0 + tx];
  {
    int kk = threadIdx.x >> 3, r = threadIdx.x & 7;
    As[kk][r] = Ae[(size_t)(k0 + kk) * 8 + r];
  }
  {
    int rr = threadIdx.x >> 5, nn = threadIdx.x & 31;
    Bs[rr][nn] = Be[(size_t)rr * Nd + n0 + nn];
  }
  __syncthreads();
#pragma unroll
  for (int i = 0; i < 4; i++) {
    int n = ty + 8 * i;
    float v = tile[tx][n];
    float l = 0.f;
#pragma unroll
    for (int r = 0; r < 8; r++) l += As[tx][r] * Bs[r][n];
    Oe[(size_t)(n0 + n) * Kd + k0 + tx] = bf16r(v + 2.0f * l);
  }
}

__global__ void k_xconv(const float* __restrict__ x, short* __restrict__ xb) {
  const int i = (blockIdx.x * 256 + threadIdx.x) * 4;
  float4 v = *(const float4*)(x + i);
  short4 s;
  s.x = bf16r(v.x); s.y = bf16r(v.y); s.z = bf16r(v.z); s.w = bf16r(v.w);
  *(short4*)(xb + i) = s;
}

// GEMM1: per expert e, C[slot, d] = Xg @ W1T^T  (M=cnt[e], N=2048, K=2048)
// epilogue: +bias, clamped GLU -> gated bf16 [off_e+slot][f]
__global__ __launch_bounds__(256) void k_gemm1(
    const short* __restrict__ Xb, const short* __restrict__ W1T,
    const float* __restrict__ bias1, const int* __restrict__ cnt,
    const int* __restrict__ offs, const int* __restrict__ list,
    short* __restrict__ gated) {
  const int e = blockIdx.z;
  const int M = cnt[e];
  const int m0 = blockIdx.y * 128;
  if (m0 >= M) return;
  const int n0 = blockIdx.x * 128;
  const short* Be = W1T + (size_t)e * 2048 * 2048;
  const int* le = list + e * 2048;
  const int off_e = offs[e];

  __shared__ __align__(16) short sA[128 * 32];
  __shared__ __align__(16) short sB[128 * 32];

  const int tid = threadIdx.x;
  const int r0 = tid >> 2;            // 0..63
  const int kq = (tid & 3) << 3;      // 0,8,16,24
  const int t0 = le[min(m0 + r0, M - 1)];
  const int t1 = le[min(m0 + r0 + 64, M - 1)];
  const short* ga0 = Xb + (size_t)t0 * 2048 + kq;
  const short* ga1 = Xb + (size_t)t1 * 2048 + kq;
  const short* gb0 = Be + (size_t)(n0 + r0) * 2048 + kq;
  const short* gb1 = Be + (size_t)(n0 + r0 + 64) * 2048 + kq;
  short* lA0 = sA + tid * 8;
  short* lA1 = sA + 2048 + tid * 8;
  short* lB0 = sB + tid * 8;
  short* lB1 = sB + 2048 + tid * 8;

  const int lane = tid & 63;
  const int wave = tid >> 6;
  const int wm = (wave & 1) * 64;
  const int wn = (wave >> 1) * 64;
  const int lm = lane & 15;
  const int quad = lane >> 4;

  f32x4 acc[4][4];
#pragma unroll
  for (int i = 0; i < 4; i++)
#pragma unroll
    for (int j = 0; j < 4; j++) acc[i][j] = (f32x4){0.f, 0.f, 0.f, 0.f};

  for (int kt = 0; kt < 64; kt++) {
    load_lds16(ga0, lA0);
    load_lds16(ga1, lA1);
    load_lds16(gb0, lB0);
    load_lds16(gb1, lB1);
    ga0 += 32; ga1 += 32; gb0 += 32; gb1 += 32;
    __syncthreads();
    bf16x8 a[4], b[4];
#pragma unroll
    for (int mi = 0; mi < 4; mi++)
      a[mi] = *(const bf16x8*)(sA + (wm + mi * 16 + lm) * 32 + quad * 8);
#pragma unroll
    for (int ni = 0; ni < 4; ni++)
      b[ni] = *(const bf16x8*)(sB + (wn + ni * 16 + lm) * 32 + quad * 8);
#pragma unroll
    for (int mi = 0; mi < 4; mi++)
#pragma unroll
      for (int ni = 0; ni < 4; ni++)
        acc[mi][ni] = __builtin_amdgcn_mfma_f32_16x16x32_bf16(a[mi], b[ni], acc[mi][ni], 0, 0, 0);
    __syncthreads();
  }

  const float* be = bias1 + e * 2048;
#pragma unroll
  for (int mi = 0; mi < 4; mi++) {
    const int rbase = m0 + wm + mi * 16 + quad * 4;
#pragma unroll
    for (int ni = 0; ni < 4; ni++) {
      const int col = n0 + wn + ni * 16 + lm;  // d index; parity == lane parity
      const float bias = be[col];
#pragma unroll
      for (int r = 0; r < 4; r++) {
        const int slot = rbase + r;
        float val = acc[mi][ni][r] + bias;
        float other = __shfl_xor(val, 1);  // partner holds the 'up' column
        if (((lane & 1) == 0) && (slot < M)) {
          float g = fminf(val, 7.f);
          float u = fminf(fmaxf(other, -7.f), 7.f);
          float glu = g / (1.f + __expf(-1.702f * g));
          float gv = (u + 1.f) * glu;
          gated[(size_t)(off_e + slot) * 1024 + (col >> 1)] = bf16r(gv);
        }
      }
    }
  }
}

// GEMM2: per expert e, C[slot, h] = gated @ W2T^T (M=cnt[e], N=2048, K=1024)
// epilogue: raw bf16 store into pairbuf[off_e+slot][h] (bias/weight applied in k_combine)
__global__ __launch_bounds__(256) void k_gemm2(
    const short* __restrict__ gated, const short* __restrict__ W2T,
    const int* __restrict__ cnt, const int* __restrict__ offs,
    short* __restrict__ pairbuf) {
  const int e = blockIdx.z;
  const int M = cnt[e];
  const int m0 = blockIdx.y * 128;
  if (m0 >= M) return;
  const int n0 = blockIdx.x * 128;
  const int off_e = offs[e];
  const short* Ae = gated + (size_t)off_e * 1024;
  const short* Be = W2T + (size_t)e * 2048 * 1024;

  __shared__ __align__(16) short sA[128 * 32];
  __shared__ __align__(16) short sB[128 * 32];

  const int tid = threadIdx.x;
  const int r0 = tid >> 2;
  const int kq = (tid & 3) << 3;
  const short* ga0 = Ae + (size_t)min(m0 + r0, M - 1) * 1024 + kq;
  const short* ga1 = Ae + (size_t)min(m0 + r0 + 64, M - 1) * 1024 + kq;
  const short* gb0 = Be + (size_t)(n0 + r0) * 1024 + kq;
  const short* gb1 = Be + (size_t)(n0 + r0 + 64) * 1024 + kq;
  short* lA0 = sA + tid * 8;
  short* lA1 = sA + 2048 + tid * 8;
  short* lB0 = sB + tid * 8;
  short* lB1 = sB + 2048 + tid * 8;

  const int lane = tid & 63;
  const int wave = tid >> 6;
  const int wm = (wave & 1) * 64;
  const int wn = (wave >> 1) * 64;
  const int lm = lane & 15;
  const int quad = lane >> 4;

  f32x4 acc[4][4];
#pragma unroll
  for (int i = 0; i < 4; i++)
#pragma unroll
    for (int j = 0; j < 4; j++) acc[i][j] = (f32x4){0.f, 0.f, 0.f, 0.f};

  for (int kt = 0; kt < 32; kt++) {
    load_lds16(ga0, lA0);
    load_lds16(ga1, lA1);
    load_lds16(gb0, lB0);
    load_lds16(gb1, lB1);
    ga0 += 32; ga1 += 32; gb0 += 32; gb1 += 32;
    __syncthreads();
    bf16x8 a[4], b[4];
#pragma unroll
    for (int mi = 0; mi < 4; mi++)
      a[mi] = *(const bf16x8*)(sA + (wm + mi * 16 + lm) * 32 + quad * 8);
#pragma unroll
    for (int ni = 0; ni < 4; ni++)
      b[ni] = *(const bf16x8*)(sB + (wn + ni * 16 + lm) * 32 + quad * 8);
#pragma unroll
    for (int mi = 0; mi < 4; mi++)
#pragma unroll
      for (int ni = 0; ni < 4; ni++)
        acc[mi][ni] = __builtin_amdgcn_mfma_f32_16x16x32_bf16(a[mi], b[ni], acc[mi][ni], 0, 0, 0);
    __syncthreads();
  }

#pragma unroll
  for (int mi = 0; mi < 4; mi++) {
#pragma unroll
    for (int r = 0; r < 4; r++) {
      const int slot = m0 + wm + mi * 16 + quad * 4 + r;
      if (slot >= M) continue;
      short* prow = pairbuf + (size_t)(off_e + slot) * 2048;
#pragma unroll
      for (int ni = 0; ni < 4; ni++) {
        const int h = n0 + wn + ni * 16 + lm;
        prow[h] = bf16r(acc[mi][ni][r]);
      }
    }
  }
}

// out[t,h] = sum_j wt_j * (pairbuf[pair_j][h] + b2[e_j][h])
__global__ __launch_bounds__(256) void k_combine(
    const short* __restrict__ pairbuf, const float* __restrict__ bias2,
    const float* __restrict__ wbuf, const int* __restrict__ offs,
    const int* __restrict__ tok_nh, const int* __restrict__ tok_pair,
    float* __restrict__ out) {
  const int t = blockIdx.x;
  const int h0 = threadIdx.x * 8;
  const int nh = tok_nh[t];
  float acc[8];
#pragma unroll
  for (int i = 0; i < 8; i++) acc[i] = 0.f;
  for (int j = 0; j < nh; j++) {
    const int p = tok_pair[t * 4 + j];
    const int e = p >> 16, slot = p & 0xffff;
    const float wt = wbuf[e * 2048 + t];
    const bf16x8 v = *(const bf16x8*)(pairbuf + (size_t)(offs[e] + slot) * 2048 + h0);
    const float4 bA = *(const float4*)(bias2 + e * 2048 + h0);
    const float4 bB = *(const float4*)(bias2 + e * 2048 + h0 + 4);
    acc[0] += wt * (bf16f(v[0]) + bA.x);
    acc[1] += wt * (bf16f(v[1]) + bA.y);
    acc[2] += wt * (bf16f(v[2]) + bA.z);
    acc[3] += wt * (bf16f(v[3]) + bA.w);
    acc[4] += wt * (bf16f(v[4]) + bB.x);
    acc[5] += wt * (bf16f(v[5]) + bB.y);
    acc[6] += wt * (bf16f(v[6]) + bB.z);
    acc[7] += wt * (bf16f(v[7]) + bB.w);
  }
  float4 oA = {acc[0], acc[1], acc[2], acc[3]};
  float4 oB = {acc[4], acc[5], acc[6], acc[7]};
  *(float4*)(out + (size_t)t * 2048 + h0) = oA;
  *(float4*)(out + (size_t)t * 2048 + h0 + 4) = oB;
}

extern "C" void kernel_launch(void* const* d_in, const int* in_sizes, int n_in,
                              void* d_out, int out_size, void* d_ws, size_t ws_size,
                              hipStream_t stream) {
  const float* x   = (const float*)d_in[0];
  const float* rw  = (const float*)d_in[1];
  const float* w1  = (const float*)d_in[2];
  const float* b1  = (const float*)d_in[3];
  const float* w2  = (const float*)d_in[4];
  const float* b2  = (const float*)d_in[5];
  const float* a1  = (const float*)d_in[6];
  const float* lb1 = (const float*)d_in[7];
  const float* a2  = (const float*)d_in[8];
  const float* lb2 = (const float*)d_in[9];
  const int* idx   = (const int*)d_in[10];
  float* out = (float*)d_out;

  char* ws = (char*)d_ws;
  int* cnt     = (int*)(ws);
  int* offs    = (int*)(ws + 64);
  int* tok_nh  = (int*)(ws + 128);           // 8 KB
  float* wbuf  = (float*)(ws + 16384);       // 64 KB
  int* list    = (int*)(ws + 81920);         // 64 KB
  int* tok_pair= (int*)(ws + 147456);        // 32 KB
  short* Xb    = (short*)(ws + (1ull << 20));        // 8 MB
  short* gated = (short*)(ws + 9437184ull);          // 16 MB
  short* W2T   = (short*)(ws + 26214400ull);         // 32 MB
  short* W1T   = (short*)(ws + 59768832ull);         // 64 MB
  short* pairbuf = (short*)(ws + 59768832ull);       // ALIASES W1T (dead after gemm1)

  hipMemsetAsync(cnt, 0, 64, stream);

  k_route<<<dim3(8), dim3(256), 0, stream>>>(idx, rw, wbuf, cnt, list, tok_nh, tok_pair);
  k_prefix<<<dim3(1), dim3(64), 0, stream>>>(cnt, offs);
  k_wprep<<<dim3(64, 64, 8), dim3(256), 0, stream>>>(w1, a1, lb1, W1T, 2048, 2048);
  k_wprep<<<dim3(64, 32, 8), dim3(256), 0, stream>>>(w2, a2, lb2, W2T, 1024, 2048);
  k_xconv<<<dim3(4096), dim3(256), 0, stream>>>(x, Xb);
  k_gemm1<<<dim3(16, 16, 8), dim3(256), 0, stream>>>(Xb, W1T, b1, cnt, offs, list, gated);
  k_gemm2<<<dim3(16, 16, 8), dim3(256), 0, stream>>>(gated, W2T, cnt, offs, pairbuf);
  k_combine<<<dim3(2048), dim3(256), 0, stream>>>(pairbuf, b2, wbuf, offs, tok_nh, tok_pair, out);
}